// Round 2
// baseline (1232.252 us; speedup 1.0000x reference)
//
#include <hip/hip_runtime.h>
#include <hip/hip_bf16.h>
#include <stdint.h>

typedef __attribute__((ext_vector_type(8))) short short8v;
typedef __attribute__((ext_vector_type(4))) short short4v;
typedef __attribute__((ext_vector_type(4))) float floatx4;

#define K_DIM   23232
#define BATCH   4096
#define M_TOT   8192
#define BM      128      // fused-fallback tile
#define BMG     256      // main gemm M-tile (4 m-frags per wave)
#define BN      176
#define BK      64
#define N_PAD   528
#define N_REAL  520

__device__ __forceinline__ float clamp01(float x) {
    return fminf(fmaxf(x, 0.0f), 1.0f);
}

__device__ __forceinline__ short8v cvt8(float4 a, float4 b) {
    union { short8v s; __hip_bfloat16 h[8]; } u;
    u.h[0] = __float2bfloat16(a.x); u.h[1] = __float2bfloat16(a.y);
    u.h[2] = __float2bfloat16(a.z); u.h[3] = __float2bfloat16(a.w);
    u.h[4] = __float2bfloat16(b.x); u.h[5] = __float2bfloat16(b.y);
    u.h[6] = __float2bfloat16(b.z); u.h[7] = __float2bfloat16(b.w);
    return u.s;
}

__device__ __forceinline__ short4v cvt4(float4 a) {
    union { short4v s; __hip_bfloat16 h[4]; } u;
    u.h[0] = __float2bfloat16(a.x); u.h[1] = __float2bfloat16(a.y);
    u.h[2] = __float2bfloat16(a.z); u.h[3] = __float2bfloat16(a.w);
    return u.s;
}

#define GLOAD_LDS16(g, l) __builtin_amdgcn_global_load_lds(               \
    (const __attribute__((address_space(1))) void*)(g),                   \
    (__attribute__((address_space(3))) void*)(l), 16, 0, 0)

// ------------- Kernel 0: ftw fp32 -> bf16 (B only; tiny, ~73 MB) ------------
// B[528][23232] = [ftw ; zeros(8 rows)]
__global__ __launch_bounds__(256) void convert_B(
    const float* __restrict__ ftw, __hip_bfloat16* __restrict__ B)
{
    const size_t totalB = (size_t)N_PAD * K_DIM;
    const size_t realB  = (size_t)N_REAL * K_DIM;   // multiple of 8
    size_t idx    = ((size_t)blockIdx.x * blockDim.x + threadIdx.x) * 8;
    size_t stride = (size_t)gridDim.x * blockDim.x * 8;

    for (size_t i = idx; i < totalB; i += stride) {
        if (i < realB) {
            float4 v0 = *(const float4*)(ftw + i);
            float4 v1 = *(const float4*)(ftw + i + 4);
            *(short8v*)(B + i) = cvt8(v0, v1);
        } else {
            *(short8v*)(B + i) = (short8v){0,0,0,0,0,0,0,0};
        }
    }
}

// ------------- Kernel 1: fused-convert MFMA GEMM ----------------------------
// part[z][m][n] = sum_{k in chunk z} A[m][k] * B[n][k]
//   A rows come straight from f1/f2 (fp32), converted in-register and written
//   to XOR-swizzled LDS via ds_write_b64 (reg-staging makes dest-swizzle
//   legal). B is bf16, staged by global_load_lds with pre-swizzled source.
// Swizzle map (both paths): physical 16B-slot p of row r holds logical slot
//   p ^ (r&7); fragment reads XOR the same way -> ~2-way banks (free).
__global__ __launch_bounds__(256, 2) void ft_gemm_af32(
    const float* __restrict__ f1, const float* __restrict__ f2,
    const __hip_bfloat16* __restrict__ B,
    float* __restrict__ part, int kiters)
{
    __shared__ __align__(16) __hip_bfloat16 As[BMG][BK];  // 32 KB swizzled
    __shared__ __align__(16) __hip_bfloat16 Bs[BN][BK];   // 22 KB linear (DMA)

    const int t    = threadIdx.x;
    const int w    = t >> 6;
    const int lane = t & 63;
    const int quad = lane >> 4;
    const int l16  = lane & 15;
    const int r7   = l16 & 7;

    // XCD-aware bijective swizzle (gridDim.x % 8 == 0). x-fastest logical id
    // keeps the 3 N-siblings of one (y,z) panel on one XCD -> L2 reuse of A.
    const int cpx = gridDim.x >> 3;
    const int h   = blockIdx.x;
    const int lid = (h & 7) * cpx + (h >> 3);
    const int xb  = lid % 3;
    const int rst = lid / 3;
    const int yb  = rst & 31;                 // 32 M-tiles
    const int zb  = rst >> 5;

    const int n0 = xb * BN;
    const int m0 = yb * BMG;
    int k0 = zb * kiters * BK;
    const int kEnd = k0 + kiters * BK;

    // BMG=256 divides the 4096 boundary, so the whole tile is in f1 or f2.
    const float* __restrict__ srcA =
        (m0 < BATCH) ? (f1 + (size_t)m0 * K_DIM)
                     : (f2 + (size_t)(m0 - BATCH) * K_DIM);

    // B DMA staging coords (wave-issue covers rows R..R+7):
    // lane l -> row R+(l>>3), source slot (l&7)^(l>>3) (pre-swizzle).
    const int arow = lane >> 3;
    const int acol = ((lane & 7) ^ (lane >> 3)) * 8;

    // A reg staging coords: iteration it covers rows it*16..it*16+15.
    // thread t -> row it*16 + (t>>4), float4-col c4 = t&15.
    const int tr  = t >> 4;
    const int c4  = t & 15;
    const int ps  = (c4 >> 1) ^ (tr & 7);     // row&7 == tr&7 (it*16 % 8 == 0)
    char* const aLds = (char*)&As[0][0] + tr * 128 + ps * 16 + (c4 & 1) * 8;
    const float* const aG = srcA + (size_t)tr * K_DIM + c4 * 4;

    floatx4 acc[4][11];
#pragma unroll
    for (int i = 0; i < 4; ++i)
#pragma unroll
        for (int j = 0; j < 11; ++j)
            acc[i][j] = (floatx4){0.f, 0.f, 0.f, 0.f};

    for (; k0 < kEnd; k0 += BK) {
        __syncthreads();
        // B: async DMA (in flight while we reg-stage A)
        for (int R = w * 8; R < BN; R += 32) {
            const __hip_bfloat16* g =
                B + (size_t)(n0 + R + arow) * K_DIM + k0 + acol;
            GLOAD_LDS16(g, &Bs[R][0]);
        }
        // A: 16 float4 loads, cvt to bf16, swizzled ds_write (groups of 4)
        float4 av[4];
#pragma unroll
        for (int g4 = 0; g4 < 4; ++g4) {
#pragma unroll
            for (int j = 0; j < 4; ++j) {
                int it = g4 * 4 + j;
                av[j] = *(const float4*)(aG + (size_t)(it * 16) * K_DIM + k0);
            }
#pragma unroll
            for (int j = 0; j < 4; ++j) {
                int it = g4 * 4 + j;
                *(short4v*)(aLds + it * 2048) = cvt4(av[j]);
            }
        }
        __syncthreads();
#pragma unroll
        for (int ks = 0; ks < BK; ks += 32) {
            const int slot = ((ks >> 3) + quad) ^ r7;   // swizzled 16B slot
            short8v a[4];
#pragma unroll
            for (int mi = 0; mi < 4; ++mi)
                a[mi] = *(const short8v*)(&As[w * 64 + mi * 16 + l16][slot * 8]);
#pragma unroll
            for (int nf = 0; nf < 11; ++nf) {
                short8v b = *(const short8v*)(&Bs[nf * 16 + l16][slot * 8]);
#pragma unroll
                for (int mi = 0; mi < 4; ++mi)
                    acc[mi][nf] = __builtin_amdgcn_mfma_f32_16x16x32_bf16(
                        a[mi], b, acc[mi][nf], 0, 0, 0);
            }
        }
    }

    float* __restrict__ dst = part + (size_t)zb * ((size_t)M_TOT * N_PAD);
#pragma unroll
    for (int mi = 0; mi < 4; ++mi) {
#pragma unroll
        for (int nf = 0; nf < 11; ++nf) {
            int gn = n0 + nf * 16 + l16;
#pragma unroll
            for (int r = 0; r < 4; ++r) {
                int gm = m0 + w * 64 + mi * 16 + quad * 4 + r;
                dst[(size_t)gm * N_PAD + gn] = acc[mi][nf][r];
            }
        }
    }
}

// ------------- Kernel 1 (fallback): fused-convert GEMM (round-1, proven) ----
__global__ __launch_bounds__(256) void ft_gemm_fused(
    const float* __restrict__ f1, const float* __restrict__ f2,
    const float* __restrict__ ftw, float* __restrict__ part, int kiters)
{
    __shared__ __align__(16) __hip_bfloat16 As[BM][72];
    __shared__ __align__(16) __hip_bfloat16 Bs[BN][72];

    const int t    = threadIdx.x;
    const int w    = t >> 6;
    const int lane = t & 63;
    const int quad = lane >> 4;
    const int l16  = lane & 15;

    const int n0 = blockIdx.x * BN;
    const int m0 = blockIdx.y * BM;
    const int z  = blockIdx.z;
    int k0 = z * kiters * BK;
    const int kEnd = k0 + kiters * BK;

    const float* __restrict__ srcA =
        (m0 < BATCH) ? (f1 + (size_t)m0 * K_DIM)
                     : (f2 + (size_t)(m0 - BATCH) * K_DIM);

    floatx4 acc[2][11];
#pragma unroll
    for (int i = 0; i < 2; ++i)
#pragma unroll
        for (int j = 0; j < 11; ++j)
            acc[i][j] = (floatx4){0.f, 0.f, 0.f, 0.f};

    for (; k0 < kEnd; k0 += BK) {
        __syncthreads();
#pragma unroll
        for (int it = 0; it < 8; ++it) {
            int c = t + it * 256, row = c >> 4, col = (c & 15) * 4;
            float4 v = *(const float4*)(srcA + (size_t)row * K_DIM + k0 + col);
            *(short4v*)(&As[row][col]) = cvt4(v);
        }
#pragma unroll
        for (int it = 0; it < 11; ++it) {
            int c = t + it * 256, row = c >> 4, col = (c & 15) * 4;
            int gn = n0 + row;
            float4 v = (gn < N_REAL)
                ? *(const float4*)(ftw + (size_t)gn * K_DIM + k0 + col)
                : make_float4(0.f, 0.f, 0.f, 0.f);
            *(short4v*)(&Bs[row][col]) = cvt4(v);
        }
        __syncthreads();
#pragma unroll
        for (int ks = 0; ks < BK; ks += 32) {
            short8v a0 = *(const short8v*)(&As[w * 32 + l16][ks + quad * 8]);
            short8v a1 = *(const short8v*)(&As[w * 32 + 16 + l16][ks + quad * 8]);
#pragma unroll
            for (int nf = 0; nf < 11; ++nf) {
                short8v b = *(const short8v*)(&Bs[nf * 16 + l16][ks + quad * 8]);
                acc[0][nf] = __builtin_amdgcn_mfma_f32_16x16x32_bf16(a0, b, acc[0][nf], 0, 0, 0);
                acc[1][nf] = __builtin_amdgcn_mfma_f32_16x16x32_bf16(a1, b, acc[1][nf], 0, 0, 0);
            }
        }
    }

    float* __restrict__ dst = part + (size_t)z * ((size_t)M_TOT * N_PAD);
#pragma unroll
    for (int mi = 0; mi < 2; ++mi) {
#pragma unroll
        for (int nf = 0; nf < 11; ++nf) {
            int gn = n0 + nf * 16 + l16;
#pragma unroll
            for (int r = 0; r < 4; ++r) {
                int gm = m0 + w * 32 + mi * 16 + quad * 4 + r;
                dst[(size_t)gm * N_PAD + gn] = acc[mi][nf][r];
            }
        }
    }
}

// ------------- Kernel 2: per-sample MLP tail (compile-time KSPLIT) ----------
template<int KS>
__global__ __launch_bounds__(256) void nnue_tail_t(
    const float* __restrict__ part,
    const int*   __restrict__ bucket,
    const float* __restrict__ ft_b,
    const float* __restrict__ h1_w, const float* __restrict__ h1_b,
    const float* __restrict__ h2_w, const float* __restrict__ h2_b,
    const float* __restrict__ out_w, const float* __restrict__ out_b,
    float* __restrict__ out)
{
    const int m = blockIdx.x;
    const int b = bucket[m];
    const size_t sz = (size_t)M_TOT * N_PAD;

    __shared__ float ft[1024];
    __shared__ float h1s[16];

    const float* p1 = part + (size_t)m * N_PAD;
    const float* p2 = part + (size_t)(m + BATCH) * N_PAD;

    // phase 1: ft accumulation — one float4 per thread, KS independent loads
    {
        const int t  = threadIdx.x;
        const float* pr = (t < 128) ? p1 : p2;
        const int ci = (t & 127) * 4;
        float4 acc = *(const float4*)(ft_b + ci);
#pragma unroll
        for (int s = 0; s < KS; ++s) {
            float4 v = *(const float4*)(pr + ci + s * sz);
            acc.x += v.x; acc.y += v.y; acc.z += v.z; acc.w += v.w;
        }
        float4 r;
        r.x = clamp01(acc.x); r.y = clamp01(acc.y);
        r.z = clamp01(acc.z); r.w = clamp01(acc.w);
        *(float4*)(ft + t * 4) = r;
    }
    __syncthreads();

    const int w    = threadIdx.x >> 6;
    const int lane = threadIdx.x & 63;

#pragma unroll
    for (int i = 0; i < 4; ++i) {
        int row = b * 16 + w * 4 + i;
        const float* wr = h1_w + (size_t)row * 1024;
        float s = 0.f;
#pragma unroll
        for (int c = 0; c < 16; ++c)
            s += ft[c * 64 + lane] * wr[c * 64 + lane];
#pragma unroll
        for (int off = 32; off > 0; off >>= 1)
            s += __shfl_down(s, off);
        if (lane == 0) h1s[w * 4 + i] = clamp01(s + h1_b[row]);
    }
    __syncthreads();

    if (threadIdx.x < 32) {
        int i = threadIdx.x;
        const float* wr = h2_w + (size_t)(b * 32 + i) * 16;
        float s = h2_b[b * 32 + i];
#pragma unroll
        for (int j = 0; j < 16; ++j) s += wr[j] * h1s[j];
        float prod = clamp01(s) * out_w[b * 32 + i];
#pragma unroll
        for (int off = 16; off > 0; off >>= 1)
            prod += __shfl_down(prod, off);
        if (i == 0) {
            float v1 = 0.f, v2 = 0.f;
#pragma unroll
            for (int s2 = 0; s2 < KS; ++s2) {
                v1 += p1[512 + b + s2 * sz];
                v2 += p2[512 + b + s2 * sz];
            }
            // FV_SCALE * 2^FT_SHIFT / 2^SHIFT = 0.25 ; psqt = 0.5*(v1-v2)
            out[m] = prod + out_b[b] + 0.125f * (v1 - v2);
        }
    }
}

extern "C" void kernel_launch(void* const* d_in, const int* in_sizes, int n_in,
                              void* d_out, int out_size, void* d_ws, size_t ws_size,
                              hipStream_t stream) {
    const int*   bucket = (const int*)  d_in[0];
    const float* f1     = (const float*)d_in[1];
    const float* f2     = (const float*)d_in[2];
    const float* ftw    = (const float*)d_in[3];
    const float* ftb    = (const float*)d_in[4];
    const float* h1w    = (const float*)d_in[5];
    const float* h1b    = (const float*)d_in[6];
    const float* h2w    = (const float*)d_in[7];
    const float* h2b    = (const float*)d_in[8];
    const float* outw   = (const float*)d_in[9];
    const float* outb   = (const float*)d_in[10];
    float* out = (float*)d_out;

    const size_t szB = (size_t)N_PAD * K_DIM * sizeof(__hip_bfloat16);  // 24.5 MB
    const size_t szP = (size_t)M_TOT * N_PAD * sizeof(float);           // 17.3 MB

    if (ws_size >= szB + 11 * szP) {
        __hip_bfloat16* Bm = (__hip_bfloat16*)d_ws;
        float* part = (float*)((char*)d_ws + szB);

        convert_B<<<1024, 256, 0, stream>>>(ftw, Bm);
        // 3 N-tiles x 32 M-tiles x 11 K-chunks, flattened for XCD swizzle
        ft_gemm_af32<<<dim3(3 * 32 * 11), 256, 0, stream>>>(f1, f2, Bm, part, 33);
        nnue_tail_t<11><<<BATCH, 256, 0, stream>>>(part, bucket, ftb,
                                                   h1w, h1b, h2w, h2b,
                                                   outw, outb, out);
    } else {
        // low-workspace fallback: fused 128-tile GEMM, ksplit = 3
        float* part = (float*)d_ws;
        dim3 grid1(3, 64, 3);
        ft_gemm_fused<<<grid1, 256, 0, stream>>>(f1, f2, ftw, part, 121);
        nnue_tail_t<3><<<BATCH, 256, 0, stream>>>(part, bucket, ftb,
                                                  h1w, h1b, h2w, h2b,
                                                  outw, outb, out);
    }
}